// Round 6
// baseline (327.908 us; speedup 1.0000x reference)
//
#include <hip/hip_runtime.h>
#include <hip/hip_bf16.h>

#define IN_D 16
#define ROW_F 273   // 1 + 16 + 256 floats per output row

// Fill-structured writer: each thread computes exactly ONE aligned float4 of
// the output (global float4 index m = 64*w + lane). A wave covers 256
// consecutive floats (< 273), so it touches at most 2 input rows; lanes 0..31
// hold those 32 input floats (one coalesced 128B load), operands fetched via
// __shfl. No LDS, no loops, no inter-group dependencies: every wave issues
// one load, ~32 shuffles, one 1KB-coalesced store, and retires.
__global__ __launch_bounds__(256) void TaylorExp_kernel(
    const float* __restrict__ x, float4* __restrict__ out, int total_in) {
    const int lane = threadIdx.x & 63;
    const int w = blockIdx.x * 4 + (threadIdx.x >> 6);   // global wave id
    const unsigned f0 = 256u * (unsigned)w;              // first float of wave
    const unsigned r0 = f0 / ROW_F;                      // first row (magic-div)

    // rows r0, r0+1 input floats: x[r0*16 .. r0*16+31]
    float v = 0.0f;
    {
        int idx = (int)(r0 * IN_D) + lane;
        if (lane < 32 && idx < total_in) v = x[idx];
    }

    const float QS = 0.17677669529663689f;  // 1/(sqrt(2)*sqrt(16))
    const int m = w * 64 + lane;            // global float4 index
    const int rloc = 4 * m - (int)(r0 * ROW_F);  // in [0, 272] for k=0

    float4 o;
    float* op = &o.x;
    #pragma unroll
    for (int k = 0; k < 4; ++k) {
        int t = rloc + k;                // may cross into row r0+1 (t >= 273)
        int hi = t >= ROW_F;
        int c = hi ? t - ROW_F : t;      // column within its row
        int s = hi ? 16 : 0;             // shuffle base for the source row
        int q = c - 17;
        bool quad = q >= 0;
        int ia = quad ? (q >> 4) : (c > 0 ? c - 1 : 0);
        int ib = quad ? (q & 15) : 0;
        float a = __shfl(v, s + ia, 64);
        float b = __shfl(v, s + ib, 64);
        op[k] = quad ? (a * b * QS) : ((c == 0) ? 1.0f : a * 0.5f);
    }
    out[m] = o;
}

extern "C" void kernel_launch(void* const* d_in, const int* in_sizes, int n_in,
                              void* d_out, int out_size, void* d_ws, size_t ws_size,
                              hipStream_t stream) {
    const float* x = (const float*)d_in[0];
    float4* out = (float4*)d_out;
    const int total_in = in_sizes[0];        // 4,194,304 floats
    // out_size = 71,565,312 floats = 17,891,328 float4 = 69,888 blocks exactly
    const int nv4 = out_size / 4;
    const int grid = nv4 / 256;              // exact; no tail

    TaylorExp_kernel<<<grid, 256, 0, stream>>>(x, out, total_in);
}